// Round 1
// baseline (37.366 us; speedup 1.0000x reference)
//
#include <hip/hip_runtime.h>

// Problem constants (match reference)
constexpr int BN     = 4194304;  // batch
constexpr int C      = 9;        // classes
constexpr int TPB    = 256;      // threads per block
constexpr int TILE   = 1024;     // rows staged per block-iteration
constexpr int NTILES = BN / TILE;        // 4096
constexpr int NBLK   = 1024;             // grid size (4 blocks/CU x 256 CUs)

__global__ __launch_bounds__(TPB) void loss_main(
    const float* __restrict__ pred_probs,   // [B,9]
    const int*   __restrict__ true_class,   // [B]
    const float* __restrict__ pred_points,  // [B]
    const float* __restrict__ true_points,  // [B]
    double*      __restrict__ partials)     // [NBLK*2]
{
    __shared__ float lds[TILE * C];              // 36864 B
    float4* lds4 = reinterpret_cast<float4*>(lds);
    const float4* pp4 = reinterpret_cast<const float4*>(pred_probs);
    const float4* a4  = reinterpret_cast<const float4*>(pred_points);
    const float4* b4  = reinterpret_cast<const float4*>(true_points);

    const int t = threadIdx.x;
    float mse_acc = 0.f;
    float ce_acc  = 0.f;

    for (int tile = blockIdx.x; tile < NTILES; tile += gridDim.x) {
        // ---- stage 1024 rows x 9 floats = 2304 float4, coalesced ----
        const float4* src = pp4 + (size_t)tile * (TILE * C / 4);
        #pragma unroll
        for (int k = 0; k < 9; ++k) {
            lds4[t + k * TPB] = src[t + k * TPB];
        }
        // ---- MSE part: 1024 points per tile = 256 float4 each array ----
        {
            float4 a = a4[(size_t)tile * (TILE / 4) + t];
            float4 b = b4[(size_t)tile * (TILE / 4) + t];
            float d0 = a.x - b.x, d1 = a.y - b.y, d2 = a.z - b.z, d3 = a.w - b.w;
            mse_acc += d0 * d0 + d1 * d1 + d2 * d2 + d3 * d3;
        }
        __syncthreads();
        // ---- per-row CE: 4 rows per thread from LDS ----
        #pragma unroll
        for (int r = 0; r < TILE / TPB; ++r) {
            const int lrow = t + r * TPB;
            const int grow = tile * TILE + lrow;
            const float* row = lds + lrow * C;
            float m = row[0];
            int am = 0;
            #pragma unroll
            for (int j = 1; j < C; ++j) {
                float v = row[j];
                if (v > m) { m = v; am = j; }
            }
            float se = 0.f;
            #pragma unroll
            for (int j = 0; j < C; ++j) se += __expf(row[j] - m);
            const int tc = true_class[grow];
            const float ce_i = m + __logf(se) - row[tc];
            int d = am - tc; if (d < 0) d = -d;
            ce_acc += (float)(d + 1) * ce_i;
        }
        __syncthreads();
    }

    // ---- block reduction: wave shfl in double, then LDS across waves ----
    double mse_d = (double)mse_acc;
    double ce_d  = (double)ce_acc;
    #pragma unroll
    for (int off = 32; off > 0; off >>= 1) {
        mse_d += __shfl_down(mse_d, off, 64);
        ce_d  += __shfl_down(ce_d, off, 64);
    }
    __shared__ double wsum[(TPB / 64) * 2];
    const int wid = t >> 6;
    if ((t & 63) == 0) { wsum[wid * 2] = mse_d; wsum[wid * 2 + 1] = ce_d; }
    __syncthreads();
    if (t == 0) {
        double ms = 0.0, cs = 0.0;
        #pragma unroll
        for (int w = 0; w < TPB / 64; ++w) { ms += wsum[w * 2]; cs += wsum[w * 2 + 1]; }
        partials[(size_t)blockIdx.x * 2]     = ms;
        partials[(size_t)blockIdx.x * 2 + 1] = cs;
    }
}

__global__ __launch_bounds__(256) void loss_finalize(
    const double* __restrict__ partials, float* __restrict__ out)
{
    const int t = threadIdx.x;
    double ms = 0.0, cs = 0.0;
    for (int b = t; b < NBLK; b += 256) {
        ms += partials[(size_t)b * 2];
        cs += partials[(size_t)b * 2 + 1];
    }
    #pragma unroll
    for (int off = 32; off > 0; off >>= 1) {
        ms += __shfl_down(ms, off, 64);
        cs += __shfl_down(cs, off, 64);
    }
    __shared__ double w[8];
    const int wid = t >> 6;
    if ((t & 63) == 0) { w[wid * 2] = ms; w[wid * 2 + 1] = cs; }
    __syncthreads();
    if (t == 0) {
        double M = 0.0, Cs = 0.0;
        #pragma unroll
        for (int i = 0; i < 4; ++i) { M += w[i * 2]; Cs += w[i * 2 + 1]; }
        const double mse = M / (double)BN;
        const double ce  = Cs / (double)BN;
        out[0] = (float)(mse + ce);   // loss = mse + ALPHA*ce, ALPHA=1
        out[1] = (float)mse;
        out[2] = (float)ce;
    }
}

extern "C" void kernel_launch(void* const* d_in, const int* in_sizes, int n_in,
                              void* d_out, int out_size, void* d_ws, size_t ws_size,
                              hipStream_t stream) {
    const float* pred_probs  = (const float*)d_in[0];
    const int*   true_class  = (const int*)d_in[1];
    const float* pred_points = (const float*)d_in[2];
    const float* true_points = (const float*)d_in[3];
    float*  out      = (float*)d_out;
    double* partials = (double*)d_ws;   // NBLK*2 doubles = 16 KB

    loss_main<<<NBLK, TPB, 0, stream>>>(pred_probs, true_class,
                                        pred_points, true_points, partials);
    loss_finalize<<<1, 256, 0, stream>>>(partials, out);
}